// Round 1
// baseline (136.399 us; speedup 1.0000x reference)
//
#include <hip/hip_runtime.h>
#include <cstdint>
#include <cstddef>

// ---------------- workspace layout (bytes) ----------------
// act   : uint64[4][8][9][1024]  bit-packed activations, index ((a*8+b)*9+c)*1024+l
// wbits : uint64[256][9]         weight sign bits (1 = +1)
// q8    : uint8[8][64][1024]     4-bit activation codes
// U     : int[576]               per-(i9) window bit counts  (i9 = ch*9+k)
// S1    : int[2304]              per-(o,c) exact integer sum of lin
// S2    : int[2304]              per-(o,c) sum of lin^2 (slow path only)
// MUG   : float2[2304]           (mu, gamma/sqrt(var+eps)) slow path only
// flag  : int[256]               fast-path flag per output channel
static const size_t OFF_ACT  = 0;                       // 2359296 B
static const size_t OFF_W    = OFF_ACT + 2359296;       // 18432 B
static const size_t OFF_Q    = OFF_W   + 18432;         // 524288 B
static const size_t OFF_U    = OFF_Q   + 524288;        // 2304 B
static const size_t OFF_S1   = OFF_U   + 2304;          // 9216 B
static const size_t OFF_S2   = OFF_S1  + 9216;          // 9216 B
static const size_t OFF_MUG  = OFF_S2  + 9216;          // 18432 B
static const size_t OFF_FLAG = OFF_MUG + 18432;         // 1024 B

#define LT 32  // l-tile in output kernel

// q = rint(clip(x,0,1)*15)  -- round-half-even matches jnp.round
__global__ __launch_bounds__(256) void k_quant(const float* __restrict__ x,
                                               uint8_t* __restrict__ q, int n) {
  int i = blockIdx.x * 256 + threadIdx.x;
  if (i < n) {
    float v = x[i];
    v = fminf(fmaxf(v, 0.f), 1.f);
    q[i] = (uint8_t)(int)rintf(v * 15.f);
  }
}

// one wave per output channel: mean over 576 weights (double), ballot sign bits
__global__ __launch_bounds__(64) void k_wpack(const float* __restrict__ w,
                                              uint64_t* __restrict__ wbits) {
  int o = blockIdx.x;
  int lane = threadIdx.x;  // 0..63
  const float* row = w + (size_t)o * 576;
  double s = 0.0;
  for (int k = lane; k < 576; k += 64) s += (double)row[k];
  for (int off = 32; off; off >>= 1) s += __shfl_down(s, off, 64);
  s = __shfl(s, 0, 64);
  float mean = (float)(s / 576.0);
  for (int c = 0; c < 9; ++c) {
    float v = row[c * 64 + lane];
    unsigned long long m = __ballot((v - mean) > 0.f);
    if (lane == 0) wbits[o * 9 + c] = (uint64_t)m;
  }
}

// pack activation bits: thread per (b,c,l); bit j of chunk c = C9 index c*64+j
__global__ __launch_bounds__(256) void k_apack(const uint8_t* __restrict__ q,
                                               uint64_t* __restrict__ act) {
  int idx = blockIdx.x * 256 + threadIdx.x;  // (b*9+c)*1024 + l
  if (idx >= 8 * 9 * 1024) return;
  int l = idx & 1023;
  int c = (idx >> 10) % 9;
  int b = idx / (9 * 1024);
  int h = l >> 5, ww_ = l & 31;
  uint64_t b0 = 0, b1 = 0, b2 = 0, b3 = 0;
  int base = c * 64;
#pragma unroll 8
  for (int j = 0; j < 64; ++j) {
    int i9 = base + j;
    int ch = i9 / 9;
    int k = i9 - ch * 9;
    int ki = k / 3, kj = k - ki * 3;
    int hh = h + ki - 1, ww = ww_ + kj - 1;
    uint32_t qq = 0;
    if ((unsigned)hh < 32u && (unsigned)ww < 32u)
      qq = q[(((b * 64 + ch) << 10) + (hh << 5)) + ww];
    b0 |= (uint64_t)(qq & 1) << j;
    b1 |= (uint64_t)((qq >> 1) & 1) << j;
    b2 |= (uint64_t)((qq >> 2) & 1) << j;
    b3 |= (uint64_t)((qq >> 3) & 1) << j;
  }
  size_t stride = 8 * 9 * 1024;
  size_t off = ((size_t)b * 9 + c) * 1024 + l;
  act[0 * stride + off] = b0;
  act[1 * stride + off] = b1;
  act[2 * stride + off] = b2;
  act[3 * stride + off] = b3;
}

// per input channel: window sums of popc4(q) over the 9 shifted 31/32-row rects
__global__ __launch_bounds__(256) void k_rect(const uint8_t* __restrict__ q,
                                              int* __restrict__ U) {
  int ch = blockIdx.x;
  int tid = threadIdx.x;
  int vals[9];  // T,R0,R31,C0,C31,X00,X0_31,X31_0,X31_31
#pragma unroll
  for (int k = 0; k < 9; ++k) vals[k] = 0;
  for (int idx = tid; idx < 8 * 1024; idx += 256) {
    int b = idx >> 10, hw = idx & 1023;
    int h = hw >> 5, w = hw & 31;
    int v = __popc((unsigned)q[((b * 64 + ch) << 10) + hw]);
    vals[0] += v;
    if (h == 0) vals[1] += v;
    if (h == 31) vals[2] += v;
    if (w == 0) vals[3] += v;
    if (w == 31) vals[4] += v;
    if (h == 0 && w == 0) vals[5] += v;
    if (h == 0 && w == 31) vals[6] += v;
    if (h == 31 && w == 0) vals[7] += v;
    if (h == 31 && w == 31) vals[8] += v;
  }
#pragma unroll
  for (int k = 0; k < 9; ++k)
    for (int off = 32; off; off >>= 1) vals[k] += __shfl_down(vals[k], off, 64);
  __shared__ int red[9][4];
  int wid = tid >> 6, lane = tid & 63;
  if (lane == 0)
    for (int k = 0; k < 9; ++k) red[k][wid] = vals[k];
  __syncthreads();
  if (tid == 0) {
    int t[9];
    for (int k = 0; k < 9; ++k) t[k] = red[k][0] + red[k][1] + red[k][2] + red[k][3];
    for (int ki = 0; ki < 3; ++ki)
      for (int kj = 0; kj < 3; ++kj) {
        int u = t[0];
        if (ki == 0) u -= t[2]; else if (ki == 2) u -= t[1];
        if (kj == 0) u -= t[4]; else if (kj == 2) u -= t[3];
        if (ki == 0 && kj == 0) u += t[8];
        if (ki == 0 && kj == 2) u += t[7];
        if (ki == 2 && kj == 0) u += t[6];
        if (ki == 2 && kj == 2) u += t[5];
        U[ch * 9 + ki * 3 + kj] = u;
      }
  }
}

__global__ __launch_bounds__(256) void k_flag(const float* __restrict__ gamma,
                                              const float* __restrict__ beta,
                                              int* __restrict__ flag) {
  int o = threadIdx.x;
  if (o < 256) flag[o] = (beta[o] == 0.f && gamma[o] > 0.f) ? 1 : 0;
}

// S1[o][c] = 2*sum_{j: w+} cnt_j - sum_j cnt_j ; cnt_j[c] = U[c*64+j]
__global__ __launch_bounds__(256) void k_s1(const uint64_t* __restrict__ wbits,
                                            const int* __restrict__ U,
                                            int* __restrict__ S1) {
  __shared__ int Ush[576];
  int tid = threadIdx.x;
  for (int t = tid; t < 576; t += 256) Ush[t] = U[t];
  __syncthreads();
  int gid = blockIdx.x * 256 + tid;  // 0..2303
  if (gid >= 2304) return;
  int o = gid / 9, c = gid - o * 9;
  uint64_t wv = wbits[o * 9 + c];
  int tot = 0, pos = 0;
#pragma unroll 8
  for (int j = 0; j < 64; ++j) {
    int cnt = Ush[c * 64 + j];
    tot += cnt;
    if ((wv >> j) & 1) pos += cnt;
  }
  S1[gid] = 2 * pos - tot;
}

// slow-path S2 (only for channels with beta!=0 or gamma<=0; never hit with this data)
__global__ __launch_bounds__(256) void k_stats_slow(const uint64_t* __restrict__ act,
                                                    const uint64_t* __restrict__ wbits,
                                                    const int* __restrict__ flag,
                                                    int* __restrict__ S2) {
  int o = blockIdx.x, c = blockIdx.y;
  if (flag[o]) return;
  uint64_t wv = wbits[o * 9 + c];
  int s2 = 0;
  for (int i = threadIdx.x; i < 32768; i += 256) {
    int bp = i >> 10, l = i & 1023;
    int a = bp >> 3, b = bp & 7;
    uint64_t av = act[((size_t)(a * 8 + b) * 9 + c) * 1024 + l];
    int lin = 2 * __popcll(av & wv) - __popcll(av);
    s2 += lin * lin;
  }
  for (int off = 32; off; off >>= 1) s2 += __shfl_down(s2, off, 64);
  __shared__ int sh[4];
  int wid = threadIdx.x >> 6;
  if ((threadIdx.x & 63) == 0) sh[wid] = s2;
  __syncthreads();
  if (threadIdx.x == 0) S2[o * 9 + c] = sh[0] + sh[1] + sh[2] + sh[3];
}

__global__ __launch_bounds__(256) void k_bnparam(const int* __restrict__ S1,
                                                 const int* __restrict__ S2,
                                                 const float* __restrict__ gamma,
                                                 const float* __restrict__ beta,
                                                 const int* __restrict__ flag,
                                                 float2* __restrict__ MUG) {
  int i = blockIdx.x * 256 + threadIdx.x;
  if (i >= 2304) return;
  int o = i / 9;
  if (flag[o]) return;
  float mu = (float)S1[i] * (1.f / 32768.f);
  float ex2 = (float)S2[i] * (1.f / 32768.f);
  float var = ex2 - mu * mu;
  if (var < 0.f) var = 0.f;
  float g = gamma[o] / sqrtf(var + 1e-5f);
  MUG[i] = make_float2(mu, g);
}

// output: out[b][o'][l] = 2 * sum_{a,s} avec[a]*wvec[s]* sum_c sign(lin - mu)
__global__ __launch_bounds__(256) void k_out(const uint64_t* __restrict__ act,
                                             const uint64_t* __restrict__ wbits,
                                             const int* __restrict__ S1,
                                             const float2* __restrict__ MUG,
                                             const int* __restrict__ flag,
                                             const float* __restrict__ beta,
                                             float* __restrict__ out) {
  __shared__ uint64_t wS[128 * 9];
  __shared__ uint64_t avS[4 * 9 * LT];
  __shared__ int pcS[4 * 9 * LT];   // popc<<15
  __shared__ int s1S[128 * 9];
  __shared__ float2 mugS[128 * 9];
  __shared__ float betaS[128];
  __shared__ int flagS[128];

  int ltile = blockIdx.x;  // 0..31
  int og = blockIdx.y;     // 0..1
  int b = blockIdx.z;      // 0..7
  int tid = threadIdx.x;

  for (int t = tid; t < 4 * 9 * LT; t += 256) {
    int a = t / (9 * LT);
    int rem = t - a * 9 * LT;
    int c = rem / LT;
    int ll = rem - c * LT;
    uint64_t v = act[((size_t)(a * 8 + b) * 9 + c) * 1024 + ltile * LT + ll];
    avS[t] = v;
    pcS[t] = __popcll(v) << 15;
  }
  for (int t = tid; t < 128 * 9; t += 256) {
    int r = t / 9, c = t - r * 9;
    int o = ((r >> 6) * 128) + og * 64 + (r & 63);
    wS[t] = wbits[o * 9 + c];
    s1S[t] = S1[o * 9 + c];
    int fl = flag[o];
    mugS[t] = fl ? make_float2(0.f, 0.f) : MUG[o * 9 + c];
    if (c == 0) { betaS[r] = beta[o]; flagS[r] = fl; }
  }
  __syncthreads();

  int ll = tid & 31;
  int otid = tid >> 5;  // 0..7
  const float avec[4] = {1.f / 15.f, 2.f / 15.f, 4.f / 15.f, 8.f / 15.f};
  const float wvec[2] = {1.f / 3.f, 2.f / 3.f};

  float acc[8];
#pragma unroll
  for (int i = 0; i < 8; ++i) acc[i] = 0.f;

  for (int a = 0; a < 4; ++a) {
    uint64_t av[9];
    int pcs[9];
#pragma unroll
    for (int c = 0; c < 9; ++c) {
      av[c] = avS[(a * 9 + c) * LT + ll];
      pcs[c] = pcS[(a * 9 + c) * LT + ll];
    }
#pragma unroll
    for (int oi = 0; oi < 8; ++oi) {
      int r0 = otid * 8 + oi;
#pragma unroll
      for (int s = 0; s < 2; ++s) {
        int r = s * 64 + r0;
        if (flagS[r]) {
          int m = 0;
#pragma unroll
          for (int c = 0; c < 9; ++c) {
            // (lin<<15) vs S1 : exact integer compare equivalent of sign(lin-mu)
            int t = (__popcll(av[c] & wS[r * 9 + c]) << 16) - pcs[c];
            int s1 = s1S[r * 9 + c];
            m += (t > s1) - (t < s1);
          }
          acc[oi] += avec[a] * wvec[s] * (float)m;
        } else {
          float fm = 0.f;
          float bb = betaS[r];
#pragma unroll
          for (int c = 0; c < 9; ++c) {
            int lin = 2 * __popcll(av[c] & wS[r * 9 + c]) - (pcs[c] >> 15);
            float2 mg = mugS[r * 9 + c];
            float bn = mg.y * ((float)lin - mg.x) + bb;
            fm += (bn > 0.f) ? 1.f : ((bn < 0.f) ? -1.f : 0.f);
          }
          acc[oi] += avec[a] * wvec[s] * fm;
        }
      }
    }
  }
#pragma unroll
  for (int oi = 0; oi < 8; ++oi) {
    int op = og * 64 + otid * 8 + oi;
    out[((size_t)b * 128 + op) * 1024 + ltile * LT + ll] = 2.f * acc[oi];
  }
}

extern "C" void kernel_launch(void* const* d_in, const int* in_sizes, int n_in,
                              void* d_out, int out_size, void* d_ws, size_t ws_size,
                              hipStream_t stream) {
  const float* inputs = (const float*)d_in[0];
  const float* weight = (const float*)d_in[1];
  const float* gamma = (const float*)d_in[2];
  const float* beta = (const float*)d_in[3];
  float* out = (float*)d_out;

  char* ws = (char*)d_ws;
  uint64_t* act = (uint64_t*)(ws + OFF_ACT);
  uint64_t* wbits = (uint64_t*)(ws + OFF_W);
  uint8_t* q8 = (uint8_t*)(ws + OFF_Q);
  int* U = (int*)(ws + OFF_U);
  int* S1 = (int*)(ws + OFF_S1);
  int* S2 = (int*)(ws + OFF_S2);
  float2* MUG = (float2*)(ws + OFF_MUG);
  int* flag = (int*)(ws + OFF_FLAG);

  k_quant<<<2048, 256, 0, stream>>>(inputs, q8, 8 * 64 * 1024);
  k_wpack<<<256, 64, 0, stream>>>(weight, wbits);
  k_apack<<<288, 256, 0, stream>>>(q8, act);
  k_rect<<<64, 256, 0, stream>>>(q8, U);
  k_flag<<<1, 256, 0, stream>>>(gamma, beta, flag);
  k_s1<<<9, 256, 0, stream>>>(wbits, U, S1);
  k_stats_slow<<<dim3(256, 9), 256, 0, stream>>>(act, wbits, flag, S2);
  k_bnparam<<<9, 256, 0, stream>>>(S1, S2, gamma, beta, flag, MUG);
  k_out<<<dim3(32, 2, 8), 256, 0, stream>>>(act, wbits, S1, MUG, flag, beta, out);
}

// Round 2
// 121.748 us; speedup vs baseline: 1.1203x; 1.1203x over previous
//
#include <hip/hip_runtime.h>
#include <cstdint>
#include <cstddef>

// ---------------- workspace layout (bytes) ----------------
// act  : uint64[4][8][9][1024]   bit-packed activations, ((a*8+b)*9+c)*1024+l
// wbits: uint64[256][9]          weight sign bits (1 = +1)
// T    : int[512][9]             per-(b,ch) rect partial sums (b*576 + ch*9 + k)
// S1   : int[2304]               per-(o,c) exact integer sum of lin
// MUG  : float2[2304]            (mu, gamma/rsqrt(var+eps)) slow path only
// flag : int[256]                fast-path flag per output channel
static const size_t OFF_ACT  = 0;                  // 2359296 B
static const size_t OFF_W    = OFF_ACT + 2359296;  // 18432 B
static const size_t OFF_T    = OFF_W   + 18432;    // 18432 B
static const size_t OFF_S1   = OFF_T   + 18432;    // 9216 B
static const size_t OFF_MUG  = OFF_S1  + 9216;     // 18432 B
static const size_t OFF_FLAG = OFF_MUG + 18432;    // 1024 B

// quant + 9 rect partial sums per (b,ch); no q8 intermediate, no atomics
__global__ __launch_bounds__(256) void k_rect_f(const float* __restrict__ x,
                                                int* __restrict__ T) {
  int bid = blockIdx.x;  // (b<<6)|ch
  int tid = threadIdx.x;
  int base = bid << 10;
  int vals[9];
#pragma unroll
  for (int k = 0; k < 9; ++k) vals[k] = 0;
#pragma unroll
  for (int i = 0; i < 4; ++i) {
    int px = tid + i * 256;
    int h = px >> 5, w = px & 31;
    float v = x[base + px];
    v = fminf(fmaxf(v, 0.f), 1.f);
    int q = (int)rintf(v * 15.f);
    int pc = __popc((unsigned)q);
    vals[0] += pc;
    if (h == 0) vals[1] += pc;
    if (h == 31) vals[2] += pc;
    if (w == 0) vals[3] += pc;
    if (w == 31) vals[4] += pc;
    if (h == 0 && w == 0) vals[5] += pc;
    if (h == 0 && w == 31) vals[6] += pc;
    if (h == 31 && w == 0) vals[7] += pc;
    if (h == 31 && w == 31) vals[8] += pc;
  }
#pragma unroll
  for (int k = 0; k < 9; ++k)
    for (int off = 32; off; off >>= 1) vals[k] += __shfl_down(vals[k], off, 64);
  __shared__ int red[4][9];
  int wid = tid >> 6, lane = tid & 63;
  if (lane == 0)
#pragma unroll
    for (int k = 0; k < 9; ++k) red[wid][k] = vals[k];
  __syncthreads();
  if (tid < 9) T[bid * 9 + tid] = red[0][tid] + red[1][tid] + red[2][tid] + red[3][tid];
}

// pack activation bits straight from floats (quantize on the fly)
__global__ __launch_bounds__(256) void k_apack_f(const float* __restrict__ x,
                                                 uint64_t* __restrict__ act) {
  int idx = blockIdx.x * 256 + threadIdx.x;  // (b*9+c)*1024 + l, exact 73728
  int l = idx & 1023;
  int c = (idx >> 10) % 9;
  int b = idx / (9 * 1024);
  int h = l >> 5, w0 = l & 31;
  int i9 = c * 64;
  int ch = i9 / 9;
  int k = i9 - ch * 9;
  int ki = k / 3, kj = k - ki * 3;
  uint64_t b0 = 0, b1 = 0, b2 = 0, b3 = 0;
#pragma unroll 8
  for (int j = 0; j < 64; ++j) {
    int hh = h + ki - 1, ww = w0 + kj - 1;
    int q = 0;
    if ((unsigned)hh < 32u && (unsigned)ww < 32u) {
      float v = x[(((b * 64 + ch) << 10) + (hh << 5)) + ww];
      v = fminf(fmaxf(v, 0.f), 1.f);
      q = (int)rintf(v * 15.f);
    }
    b0 |= (uint64_t)(q & 1) << j;
    b1 |= (uint64_t)((q >> 1) & 1) << j;
    b2 |= (uint64_t)((q >> 2) & 1) << j;
    b3 |= (uint64_t)((q >> 3) & 1) << j;
    if (++kj == 3) { kj = 0; if (++ki == 3) { ki = 0; ++ch; } }
  }
  size_t stride = 8 * 9 * 1024;
  size_t off = ((size_t)b * 9 + c) * 1024 + l;
  act[0 * stride + off] = b0;
  act[1 * stride + off] = b1;
  act[2 * stride + off] = b2;
  act[3 * stride + off] = b3;
}

// one wave per output channel: weight mean+ballot, U from T, S1, flag
__global__ __launch_bounds__(64) void k_ws1(const float* __restrict__ w,
                                            const int* __restrict__ T,
                                            const float* __restrict__ gamma,
                                            const float* __restrict__ beta,
                                            uint64_t* __restrict__ wbits,
                                            int* __restrict__ S1,
                                            int* __restrict__ flag) {
  int o = blockIdx.x;
  int lane = threadIdx.x;
  const float* row = w + (size_t)o * 576;
  double s = 0.0;
  for (int kk = lane; kk < 576; kk += 64) s += (double)row[kk];
  for (int off = 32; off; off >>= 1) s += __shfl_down(s, off, 64);
  s = __shfl(s, 0, 64);
  float mean = (float)(s / 576.0);
  uint64_t wb[9];
#pragma unroll
  for (int c = 0; c < 9; ++c) {
    float v = row[c * 64 + lane];
    wb[c] = (uint64_t)__ballot((v - mean) > 0.f);
  }
  if (lane == 0) {
#pragma unroll
    for (int c = 0; c < 9; ++c) wbits[o * 9 + c] = wb[c];
    flag[o] = (beta[o] == 0.f && gamma[o] > 0.f) ? 1 : 0;
  }
  __shared__ int Tsh[576];
  __shared__ int Ush[576];
#pragma unroll
  for (int i = 0; i < 9; ++i) {
    int idx = lane + i * 64;
    int acc = 0;
#pragma unroll
    for (int b = 0; b < 8; ++b) acc += T[b * 576 + idx];
    Tsh[idx] = acc;
  }
  __syncthreads();
#pragma unroll
  for (int i = 0; i < 9; ++i) {
    int idx = lane + i * 64;
    int ch = idx / 9;
    int k = idx - ch * 9;
    int ki = k / 3, kj = k - ki * 3;
    const int* t = &Tsh[ch * 9];
    int u = t[0];
    if (ki == 0) u -= t[2]; else if (ki == 2) u -= t[1];
    if (kj == 0) u -= t[4]; else if (kj == 2) u -= t[3];
    if (ki == 0 && kj == 0) u += t[8];
    if (ki == 0 && kj == 2) u += t[7];
    if (ki == 2 && kj == 0) u += t[6];
    if (ki == 2 && kj == 2) u += t[5];
    Ush[idx] = u;
  }
  __syncthreads();
#pragma unroll
  for (int c = 0; c < 9; ++c) {
    int u = Ush[c * 64 + lane];
    int v = ((wb[c] >> lane) & 1) ? u : -u;
    for (int off = 32; off; off >>= 1) v += __shfl_down(v, off, 64);
    if (lane == 0) S1[o * 9 + c] = v;
  }
}

// gated slow path: S2 reduction + BN params, only for flag==0 channels
__global__ __launch_bounds__(256) void k_slow(const uint64_t* __restrict__ act,
                                              const uint64_t* __restrict__ wbits,
                                              const int* __restrict__ S1,
                                              const int* __restrict__ flag,
                                              const float* __restrict__ gamma,
                                              float2* __restrict__ MUG) {
  int base = blockIdx.x * 64;  // 36 blocks x 64 pairs = 2304
  __shared__ int sh[4];
  for (int p = 0; p < 64; ++p) {
    int pair = base + p;
    int o = pair / 9, c = pair - o * 9;
    if (flag[o]) continue;
    uint64_t wv = wbits[pair];
    int s2 = 0;
    for (int i = threadIdx.x; i < 32768; i += 256) {
      int bp = i >> 10, l = i & 1023;
      uint64_t av = act[((size_t)bp * 9 + c) * 1024 + l];
      int lin = 2 * __popcll(av & wv) - __popcll(av);
      s2 += lin * lin;
    }
    for (int off = 32; off; off >>= 1) s2 += __shfl_down(s2, off, 64);
    if ((threadIdx.x & 63) == 0) sh[threadIdx.x >> 6] = s2;
    __syncthreads();
    if (threadIdx.x == 0) {
      int s2t = sh[0] + sh[1] + sh[2] + sh[3];
      float mu = (float)S1[pair] * (1.f / 32768.f);
      float ex2 = (float)s2t * (1.f / 32768.f);
      float var = ex2 - mu * mu;
      if (var < 0.f) var = 0.f;
      MUG[pair] = make_float2(mu, gamma[o] / sqrtf(var + 1e-5f));
    }
    __syncthreads();
  }
}

// output: lane = pixel; weights/S1 wave-uniform (scalar loads); no LDS
__global__ __launch_bounds__(256) void k_out(const uint64_t* __restrict__ act,
                                             const uint64_t* __restrict__ wbits,
                                             const int* __restrict__ S1,
                                             const float2* __restrict__ MUG,
                                             const int* __restrict__ flag,
                                             const float* __restrict__ beta,
                                             float* __restrict__ out) {
  int ltile = blockIdx.x;  // 16 tiles of 64 px
  int og = blockIdx.y;     // 16 groups of 8 op
  int b = blockIdx.z;      // 8
  int tid = threadIdx.x;
  int lane = tid & 63;
  int wid = __builtin_amdgcn_readfirstlane(tid >> 6);  // 0..3 (wave-uniform)
  int op_base = og * 8 + wid * 2;
  int l = (ltile << 6) + lane;

  int fl[2][2];
#pragma unroll
  for (int oi = 0; oi < 2; ++oi)
#pragma unroll
    for (int s = 0; s < 2; ++s) fl[oi][s] = flag[s * 128 + op_base + oi];

  const float avec[4] = {1.f / 15.f, 2.f / 15.f, 4.f / 15.f, 8.f / 15.f};
  const float wvec[2] = {1.f / 3.f, 2.f / 3.f};

  int M[2] = {0, 0};
  float accf[2] = {0.f, 0.f};

  for (int a = 0; a < 4; ++a) {
    uint64_t av[9];
    int npa[9];
    const uint64_t* ap = act + ((size_t)(a * 8 + b) * 9) * 1024 + l;
#pragma unroll
    for (int c = 0; c < 9; ++c) {
      av[c] = ap[c * 1024];
      npa[c] = -(int)(__popcll(av[c]) << 15);
    }
#pragma unroll
    for (int oi = 0; oi < 2; ++oi) {
#pragma unroll
      for (int s = 0; s < 2; ++s) {
        int o = s * 128 + op_base + oi;
        const uint64_t* wp = wbits + o * 9;
        const int* s1p = S1 + o * 9;
        if (fl[oi][s]) {
          int m = 0;
#pragma unroll
          for (int c = 0; c < 9; ++c) {
            int p = (int)__popcll(av[c] & wp[c]);
            int d = (p << 16) + npa[c];  // (lin<<15): exact sign(lin - mu)
            int s1 = s1p[c];
            m += (d > s1) - (d < s1);
          }
          M[oi] += m << (a + s);
        } else {
          const float2* mg = MUG + o * 9;
          float bb = beta[o];
          float fm = 0.f;
#pragma unroll
          for (int c = 0; c < 9; ++c) {
            int lin = 2 * (int)__popcll(av[c] & wp[c]) + (npa[c] >> 15);
            float2 m2 = mg[c];
            float bn = m2.y * ((float)lin - m2.x) + bb;
            fm += (bn > 0.f) ? 1.f : ((bn < 0.f) ? -1.f : 0.f);
          }
          accf[oi] += avec[a] * wvec[s] * fm;
        }
      }
    }
  }
#pragma unroll
  for (int oi = 0; oi < 2; ++oi) {
    int op = op_base + oi;
    out[((size_t)b * 128 + op) * 1024 + l] = (float)M[oi] * (2.f / 45.f) + 2.f * accf[oi];
  }
}

extern "C" void kernel_launch(void* const* d_in, const int* in_sizes, int n_in,
                              void* d_out, int out_size, void* d_ws, size_t ws_size,
                              hipStream_t stream) {
  const float* inputs = (const float*)d_in[0];
  const float* weight = (const float*)d_in[1];
  const float* gamma = (const float*)d_in[2];
  const float* beta = (const float*)d_in[3];
  float* out = (float*)d_out;

  char* ws = (char*)d_ws;
  uint64_t* act = (uint64_t*)(ws + OFF_ACT);
  uint64_t* wbits = (uint64_t*)(ws + OFF_W);
  int* T = (int*)(ws + OFF_T);
  int* S1 = (int*)(ws + OFF_S1);
  float2* MUG = (float2*)(ws + OFF_MUG);
  int* flag = (int*)(ws + OFF_FLAG);

  k_rect_f<<<512, 256, 0, stream>>>(inputs, T);
  k_apack_f<<<288, 256, 0, stream>>>(inputs, act);
  k_ws1<<<256, 64, 0, stream>>>(weight, T, gamma, beta, wbits, S1, flag);
  k_slow<<<36, 256, 0, stream>>>(act, wbits, S1, flag, gamma, MUG);
  k_out<<<dim3(16, 16, 8), 256, 0, stream>>>(act, wbits, S1, MUG, flag, beta, out);
}

// Round 3
// 114.572 us; speedup vs baseline: 1.1905x; 1.0626x over previous
//
#include <hip/hip_runtime.h>
#include <cstdint>
#include <cstddef>

// ---------------- workspace layout (bytes) ----------------
// act  : uint64[4][8][9][1024]   bit-packed activations, ((a*8+b)*9+c)*1024+l
// wbits: uint64[256][9]          weight sign bits (1 = +1)
// T    : int[512][9]             per-(b,ch) rect partial sums (b*576 + ch*9 + k)
// S1   : int[2304]               per-(o,c) exact integer sum of lin
// MUG  : float2[2304]            (mu, gamma/rsqrt(var+eps)) slow path only
// flag : int[256]                fast-path flag per output channel
static const size_t OFF_ACT  = 0;                  // 2359296 B
static const size_t OFF_W    = OFF_ACT + 2359296;  // 18432 B
static const size_t OFF_T    = OFF_W   + 18432;    // 18432 B
static const size_t OFF_S1   = OFF_T   + 18432;    // 9216 B
static const size_t OFF_MUG  = OFF_S1  + 9216;     // 18432 B
static const size_t OFF_FLAG = OFF_MUG + 18432;    // 1024 B

// fused: blocks [0,512) = quant+rect partials per (b,ch); [512,800) = act bit-pack
__global__ __launch_bounds__(256) void k_prep(const float* __restrict__ x,
                                              int* __restrict__ T,
                                              uint64_t* __restrict__ act) {
  int bid = blockIdx.x;
  int tid = threadIdx.x;
  if (bid < 512) {
    // ---- rect: quantize + 9 shifted-window popc partial sums ----
    int base = bid << 10;
    int vals[9];
#pragma unroll
    for (int k = 0; k < 9; ++k) vals[k] = 0;
#pragma unroll
    for (int i = 0; i < 4; ++i) {
      int px = tid + i * 256;
      int h = px >> 5, w = px & 31;
      float v = x[base + px];
      v = fminf(fmaxf(v, 0.f), 1.f);
      int q = (int)rintf(v * 15.f);
      int pc = __popc((unsigned)q);
      vals[0] += pc;
      if (h == 0) vals[1] += pc;
      if (h == 31) vals[2] += pc;
      if (w == 0) vals[3] += pc;
      if (w == 31) vals[4] += pc;
      if (h == 0 && w == 0) vals[5] += pc;
      if (h == 0 && w == 31) vals[6] += pc;
      if (h == 31 && w == 0) vals[7] += pc;
      if (h == 31 && w == 31) vals[8] += pc;
    }
#pragma unroll
    for (int k = 0; k < 9; ++k)
      for (int off = 32; off; off >>= 1) vals[k] += __shfl_down(vals[k], off, 64);
    __shared__ int red[4][9];
    int wid = tid >> 6, lane = tid & 63;
    if (lane == 0)
#pragma unroll
      for (int k = 0; k < 9; ++k) red[wid][k] = vals[k];
    __syncthreads();
    if (tid < 9) T[bid * 9 + tid] = red[0][tid] + red[1][tid] + red[2][tid] + red[3][tid];
  } else {
    // ---- apack: pack 4 bit-planes of 64 C9-channels per (b,c,l) ----
    int idx = (bid - 512) * 256 + tid;  // (b*9+c)*1024 + l, exact 73728
    int l = idx & 1023;
    int c = (idx >> 10) % 9;
    int b = idx / (9 * 1024);
    int h = l >> 5, w0 = l & 31;
    int i9 = c * 64;
    int ch = i9 / 9;
    int k = i9 - ch * 9;
    int ki = k / 3, kj = k - ki * 3;
    uint64_t b0 = 0, b1 = 0, b2 = 0, b3 = 0;
#pragma unroll 8
    for (int j = 0; j < 64; ++j) {
      int hh = h + ki - 1, ww = w0 + kj - 1;
      int q = 0;
      if ((unsigned)hh < 32u && (unsigned)ww < 32u) {
        float v = x[(((b * 64 + ch) << 10) + (hh << 5)) + ww];
        v = fminf(fmaxf(v, 0.f), 1.f);
        q = (int)rintf(v * 15.f);
      }
      b0 |= (uint64_t)(q & 1) << j;
      b1 |= (uint64_t)((q >> 1) & 1) << j;
      b2 |= (uint64_t)((q >> 2) & 1) << j;
      b3 |= (uint64_t)((q >> 3) & 1) << j;
      if (++kj == 3) { kj = 0; if (++ki == 3) { ki = 0; ++ch; } }
    }
    size_t stride = 8 * 9 * 1024;
    size_t off = ((size_t)b * 9 + c) * 1024 + l;
    act[0 * stride + off] = b0;
    act[1 * stride + off] = b1;
    act[2 * stride + off] = b2;
    act[3 * stride + off] = b3;
  }
}

// one wave per output channel: weight mean+ballot, U from T, S1, flag,
// plus gated BN slow path (zero cost when beta==0 && gamma>0)
__global__ __launch_bounds__(64) void k_ws1(const float* __restrict__ w,
                                            const int* __restrict__ T,
                                            const float* __restrict__ gamma,
                                            const float* __restrict__ beta,
                                            const uint64_t* __restrict__ act,
                                            uint64_t* __restrict__ wbits,
                                            int* __restrict__ S1,
                                            int* __restrict__ flag,
                                            float2* __restrict__ MUG) {
  int o = blockIdx.x;
  int lane = threadIdx.x;
  const float* row = w + (size_t)o * 576;
  double s = 0.0;
  for (int kk = lane; kk < 576; kk += 64) s += (double)row[kk];
  for (int off = 32; off; off >>= 1) s += __shfl_down(s, off, 64);
  s = __shfl(s, 0, 64);
  float mean = (float)(s / 576.0);
  uint64_t wb[9];
#pragma unroll
  for (int c = 0; c < 9; ++c) {
    float v = row[c * 64 + lane];
    wb[c] = (uint64_t)__ballot((v - mean) > 0.f);
  }
  float g = gamma[o], bt = beta[o];
  int flagv = (bt == 0.f && g > 0.f) ? 1 : 0;
  if (lane == 0) {
#pragma unroll
    for (int c = 0; c < 9; ++c) wbits[o * 9 + c] = wb[c];
    flag[o] = flagv;
  }
  __shared__ int Tsh[576];
  __shared__ int Ush[576];
#pragma unroll
  for (int i = 0; i < 9; ++i) {
    int idx = lane + i * 64;
    int acc = 0;
#pragma unroll
    for (int b = 0; b < 8; ++b) acc += T[b * 576 + idx];
    Tsh[idx] = acc;
  }
  __syncthreads();
#pragma unroll
  for (int i = 0; i < 9; ++i) {
    int idx = lane + i * 64;
    int ch = idx / 9;
    int k = idx - ch * 9;
    int ki = k / 3, kj = k - ki * 3;
    const int* t = &Tsh[ch * 9];
    int u = t[0];
    if (ki == 0) u -= t[2]; else if (ki == 2) u -= t[1];
    if (kj == 0) u -= t[4]; else if (kj == 2) u -= t[3];
    if (ki == 0 && kj == 0) u += t[8];
    if (ki == 0 && kj == 2) u += t[7];
    if (ki == 2 && kj == 0) u += t[6];
    if (ki == 2 && kj == 2) u += t[5];
    Ush[idx] = u;
  }
  __syncthreads();
  int s1loc[9];
#pragma unroll
  for (int c = 0; c < 9; ++c) {
    int u = Ush[c * 64 + lane];
    int v = ((wb[c] >> lane) & 1) ? u : -u;
    for (int off = 32; off; off >>= 1) v += __shfl_down(v, off, 64);
    v = __shfl(v, 0, 64);
    s1loc[c] = v;
    if (lane == 0) S1[o * 9 + c] = v;
  }
  // gated slow path: per-(o,c) S2 reduce + BN params (never taken w/ this data)
  if (!flagv) {
    for (int c = 0; c < 9; ++c) {
      uint64_t wv = wb[c];
      int s2 = 0;
      for (int i = lane; i < 32768; i += 64) {
        uint64_t av = act[((size_t)(i >> 10) * 9 + c) * 1024 + (i & 1023)];
        int lin = 2 * __popcll(av & wv) - __popcll(av);
        s2 += lin * lin;
      }
      for (int off = 32; off; off >>= 1) s2 += __shfl_down(s2, off, 64);
      if (lane == 0) {
        float mu = (float)s1loc[c] * (1.f / 32768.f);
        float ex2 = (float)s2 * (1.f / 32768.f);
        float var = ex2 - mu * mu;
        if (var < 0.f) var = 0.f;
        MUG[o * 9 + c] = make_float2(mu, g / sqrtf(var + 1e-5f));
      }
    }
  }
}

// output: lane = pixel-pair; 2 output channels (w-slice pair) per wave.
// Weights/S1 wave-uniform -> 54 SGPRs, hoisted once. No LDS.
__global__ __launch_bounds__(256) void k_out(const uint64_t* __restrict__ act,
                                             const uint64_t* __restrict__ wbits,
                                             const int* __restrict__ S1,
                                             const float2* __restrict__ MUG,
                                             const int* __restrict__ flag,
                                             const float* __restrict__ beta,
                                             float* __restrict__ out) {
  int ltile = blockIdx.x;  // 0..7, 128 px per tile
  int og = blockIdx.y;     // 0..31
  int b = blockIdx.z;      // 0..7
  int tid = threadIdx.x;
  int lane = tid & 63;
  int wid = __builtin_amdgcn_readfirstlane(tid >> 6);  // 0..3 wave-uniform
  int op = og * 4 + wid;        // output channel 0..127
  int l = (ltile << 7) + lane * 2;

  // hoist wave-uniform weight data (SGPRs)
  uint64_t Wv[2][9];
  int Sv[2][9];
  int FL[2];
#pragma unroll
  for (int s = 0; s < 2; ++s) {
    int o = s * 128 + op;
    FL[s] = flag[o];
#pragma unroll
    for (int c = 0; c < 9; ++c) {
      Wv[s][c] = wbits[o * 9 + c];
      Sv[s][c] = S1[o * 9 + c];
    }
  }

  const float avec[4] = {1.f / 15.f, 2.f / 15.f, 4.f / 15.f, 8.f / 15.f};
  const float wvec[2] = {1.f / 3.f, 2.f / 3.f};

  int M0 = 0, M1 = 0;
  float accf[2][2] = {{0.f, 0.f}, {0.f, 0.f}};  // [s][px]

  for (int a = 0; a < 4; ++a) {
    const uint64_t* ap = act + ((size_t)(a * 8 + b) * 9) * 1024 + l;
    uint64_t av0[9], av1[9];
    int np0[9], np1[9];
#pragma unroll
    for (int c = 0; c < 9; ++c) {
      av0[c] = ap[c * 1024];      // adjacent pair -> dwordx4
      av1[c] = ap[c * 1024 + 1];
      np0[c] = -(int)(__popcll(av0[c]) << 15);
      np1[c] = -(int)(__popcll(av1[c]) << 15);
    }
#pragma unroll
    for (int s = 0; s < 2; ++s) {
      if (FL[s]) {
        int m0 = 0, m1 = 0;
#pragma unroll
        for (int c = 0; c < 9; ++c) {
          uint64_t wv = Wv[s][c];
          int s1 = Sv[s][c];
          int d0 = ((int)__popcll(av0[c] & wv) << 16) + np0[c];
          int d1 = ((int)__popcll(av1[c] & wv) << 16) + np1[c];
          m0 += (d0 > s1) - (d0 < s1);
          m1 += (d1 > s1) - (d1 < s1);
        }
        M0 += m0 << (a + s);
        M1 += m1 << (a + s);
      } else {
        int o = s * 128 + op;
        const float2* mg = MUG + o * 9;
        float bb = beta[o];
        float f0 = 0.f, f1 = 0.f;
#pragma unroll
        for (int c = 0; c < 9; ++c) {
          uint64_t wv = Wv[s][c];
          float2 m2 = mg[c];
          int l0 = 2 * (int)__popcll(av0[c] & wv) + (np0[c] >> 15);
          int l1 = 2 * (int)__popcll(av1[c] & wv) + (np1[c] >> 15);
          float bn0 = m2.y * ((float)l0 - m2.x) + bb;
          float bn1 = m2.y * ((float)l1 - m2.x) + bb;
          f0 += (bn0 > 0.f) ? 1.f : ((bn0 < 0.f) ? -1.f : 0.f);
          f1 += (bn1 > 0.f) ? 1.f : ((bn1 < 0.f) ? -1.f : 0.f);
        }
        accf[s][0] += avec[a] * wvec[s] * f0;
        accf[s][1] += avec[a] * wvec[s] * f1;
      }
    }
  }
  size_t ob = ((size_t)b * 128 + op) * 1024 + l;
  out[ob]     = (float)M0 * (2.f / 45.f) + 2.f * (accf[0][0] + accf[1][0]);
  out[ob + 1] = (float)M1 * (2.f / 45.f) + 2.f * (accf[0][1] + accf[1][1]);
}

extern "C" void kernel_launch(void* const* d_in, const int* in_sizes, int n_in,
                              void* d_out, int out_size, void* d_ws, size_t ws_size,
                              hipStream_t stream) {
  const float* inputs = (const float*)d_in[0];
  const float* weight = (const float*)d_in[1];
  const float* gamma = (const float*)d_in[2];
  const float* beta = (const float*)d_in[3];
  float* out = (float*)d_out;

  char* ws = (char*)d_ws;
  uint64_t* act = (uint64_t*)(ws + OFF_ACT);
  uint64_t* wbits = (uint64_t*)(ws + OFF_W);
  int* T = (int*)(ws + OFF_T);
  int* S1 = (int*)(ws + OFF_S1);
  float2* MUG = (float2*)(ws + OFF_MUG);
  int* flag = (int*)(ws + OFF_FLAG);

  k_prep<<<800, 256, 0, stream>>>(inputs, T, act);
  k_ws1<<<256, 64, 0, stream>>>(weight, T, gamma, beta, act, wbits, S1, flag, MUG);
  k_out<<<dim3(8, 32, 8), 256, 0, stream>>>(act, wbits, S1, MUG, flag, beta, out);
}